// Round 1
// 354.045 us; speedup vs baseline: 1.1178x; 1.1178x over previous
//
#include <hip/hip_runtime.h>
#include <cstdint>
#include <cstddef>
#include <cmath>

typedef __bf16 bf16_t;
typedef __bf16 bf16x8 __attribute__((ext_vector_type(8)));
typedef float floatx4 __attribute__((ext_vector_type(4)));

#define AS1 __attribute__((address_space(1)))
#define AS3 __attribute__((address_space(3)))

__device__ __forceinline__ void gload_lds16(const bf16_t* g, bf16_t* l) {
    __builtin_amdgcn_global_load_lds((AS1 void*)(uintptr_t)(g), (AS3 void*)(l), 16, 0, 0);
}

__device__ __forceinline__ float sigf(float x) { return 1.0f / (1.0f + __expf(-x)); }
__device__ __forceinline__ float tanhfast(float x) { return 1.0f - 2.0f / (__expf(2.0f * x) + 1.0f); }

// ------------- Fused GEMM + LSTM cell (templated M-tile) -------------
// gates(M x N) = A(M,K) @ W(N,K)^T + bias(N), then LSTM cell per element.
// Weight rows packed gate-interleaved: each lane's acc[i][0..3] are the 4
// gates (i,f,g,o) of one element column e = ((n0+wn)>>2)+(lane&15).
// LDS XOR swizzle: physical 16B chunk = logical_kchunk ^ (row&7); staging
// keeps the mandatory linear base+lane*16 global_load_lds pattern by
// permuting the per-lane *global* address (still intra-128B-segment coalesced).
// BM=128 for encoder (grid 32x32, 4 blocks/CU); BM=32 for decoder
// (grid 4x128 = 512 blocks -> 2 blocks/CU so stage-drains of one block
// overlap compute of the other; N=512 only gives 4 N-tiles).
// czero=1: layer-0 call, c-in is exactly zero -> skip the load (and the
// host-side zero-init of c entirely: layer 0 writes every element).
template<int BM>
__global__ __launch_bounds__(256, 4)
void gemm_lstm(const bf16_t* __restrict__ A, const bf16_t* __restrict__ B,
               const float* __restrict__ bias, float* __restrict__ c, int EP,
               bf16_t* __restrict__ hb, int ldH, int hoff, float* __restrict__ hf,
               int K, int ldA, int ldB, int relu, int czero)
{
    constexpr int AI = BM / 32;          // i-frags per wave = A-chunks per thread
    __shared__ bf16_t As[BM * 64];
    __shared__ bf16_t Bs[128 * 64];
    const int tid  = threadIdx.x;
    const int lane = tid & 63;
    const int w    = tid >> 6;
    const int wm   = (w & 1) * (BM / 2);
    const int wn   = (w >> 1) * 64;
    const int m0   = blockIdx.y * BM;
    const int n0   = blockIdx.x * 128;

    floatx4 zero = {0.0f, 0.0f, 0.0f, 0.0f};
    floatx4 acc[AI][4];
#pragma unroll
    for (int i = 0; i < AI; ++i)
#pragma unroll
        for (int j = 0; j < 4; ++j) acc[i][j] = zero;

    const int srow = lane >> 3;                 // staging row-in-chunk 0..7
    const int sk   = ((lane & 7) ^ srow) * 8;   // swizzled k-chunk (elements)
    const int fr   = lane & 15;                 // fragment row
    const int fx   = fr & 7;                    // read-side xor key

    const bf16_t* Ag = A + (size_t)(m0 + srow) * ldA + sk;
    const bf16_t* Bg = B + (size_t)(n0 + srow) * ldB + sk;

    for (int k0 = 0; k0 < K; k0 += 64) {
        __syncthreads();
#pragma unroll
        for (int j = 0; j < AI; ++j) {
            int r0 = (w * AI + j) * 8;
            gload_lds16(Ag + (size_t)r0 * ldA + k0, As + r0 * 64 + lane * 8);
        }
#pragma unroll
        for (int j = 0; j < 4; ++j) {
            int r0 = (w * 4 + j) * 8;
            gload_lds16(Bg + (size_t)r0 * ldB + k0, Bs + r0 * 64 + lane * 8);
        }
        __syncthreads();
#pragma unroll
        for (int kk = 0; kk < 64; kk += 32) {
            const int pc = ((((kk >> 3) + (lane >> 4)) ^ fx) << 3);
            bf16x8 af[AI], bfr[4];
#pragma unroll
            for (int i = 0; i < AI; ++i)
                af[i] = *(const bf16x8*)(As + (wm + i * 16 + fr) * 64 + pc);
#pragma unroll
            for (int j = 0; j < 4; ++j)
                bfr[j] = *(const bf16x8*)(Bs + (wn + j * 16 + fr) * 64 + pc);
#pragma unroll
            for (int i = 0; i < AI; ++i)
#pragma unroll
                for (int j = 0; j < 4; ++j)
                    acc[i][j] = __builtin_amdgcn_mfma_f32_16x16x32_bf16(af[i], bfr[j], acc[i][j], 0, 0, 0);
        }
    }

    // Fused LSTM epilogue. C/D layout: col = lane&15, row = (lane>>4)*4 + reg.
    const int crow = (lane >> 4) * 4;
    const int ccol = lane & 15;
    const int e    = ((n0 + wn) >> 2) + ccol;
    float bi[4];
#pragma unroll
    for (int j = 0; j < 4; ++j) bi[j] = bias[n0 + wn + j * 16 + ccol];

#pragma unroll
    for (int i = 0; i < AI; ++i) {
#pragma unroll
        for (int r = 0; r < 4; ++r) {
            int t = m0 + wm + i * 16 + crow + r;
            float iv = acc[i][0][r] + bi[0];
            float fv = acc[i][1][r] + bi[1];
            float gv = acc[i][2][r] + bi[2];
            float ov = acc[i][3][r] + bi[3];
            size_t cix = (size_t)t * EP + e;
            float cold = 0.0f;
            if (!czero) cold = c[cix];
            float cv = sigf(fv) * cold + sigf(iv) * tanhfast(gv);
            c[cix] = cv;
            float hv = sigf(ov) * tanhfast(cv);
            if (relu) hv = fmaxf(hv, 0.0f);
            if (hb) hb[(size_t)t * ldH + hoff + e] = (bf16_t)hv;
            else    hf[(size_t)t * EP + e] = hv;
        }
    }
}

// ---------------- Packing (interleaved-gate layout, vectorized) ----------------
// A_enc (4096 x 1152 bf16): [x(0:101) pad(101:128) h(128:1152)]
// A_dec (4096 x 1152 bf16): [enc(0:1024) h(1024:1152)]
// All pack work is independent (disjoint outputs) -> one kernel, dispatched
// by blockIdx range, removing 4 launch gaps:
//   [0,     9216) : W_enc  (16384 rows * 144 groups of 8)
//   [9216, 11520) : A_enc x+zero fill (4096 rows * 144 groups)
//   [11520,12672) : W_dec  (2048 rows * 144 groups)
//   [12672,12744) : biases (16384 enc + 2048 dec)
// Layer-0 K-trim + czero make all other buffers write-before-read, so no
// zero-init kernel is needed (ws is re-poisoned 0xAA every call):
//   cenc/cdec: fully written by layer-0 gemm (czero=1) before any read.
//   Adec h-slot: dec layer 0 runs K=1024 (h=0 term skipped), then writes it.
__global__ void pack_all(const float* __restrict__ x,
                         const float* __restrict__ eWih, const float* __restrict__ eWhh,
                         const float* __restrict__ ebih, const float* __restrict__ ebhh,
                         const float* __restrict__ dWih, const float* __restrict__ dWhh,
                         const float* __restrict__ dbih, const float* __restrict__ dbhh,
                         bf16_t* __restrict__ Aenc, bf16_t* __restrict__ Wenc,
                         bf16_t* __restrict__ Wdec,
                         float* __restrict__ bse, float* __restrict__ bsd)
{
    const int b = blockIdx.x;
    if (b < 9216) {
        // W_enc: N-pos p: g=(p>>4)&3, e=((p>>6)<<4)+(p&15); orig row g*1000+e
        // (if e<1000). Cols: [Wih(0:101) 0 Whh(128:1128) 0].
        int gid = b * 256 + threadIdx.x;
        int row = gid / 144, grp = gid - row * 144;
        int l = row >> 12, p = row & 4095;
        int g = (p >> 4) & 3, e = ((p >> 6) << 4) + (p & 15);
        int c0 = grp * 8;
        float v[8];
#pragma unroll
        for (int u = 0; u < 8; ++u) v[u] = 0.0f;
        if (e < 1000) {
            size_t r = (size_t)l * 4000 + g * 1000 + e;
            if (c0 >= 128 && c0 < 1128) {
                // Whh row stride 1000 (mult of 4), c0-128 mult of 8 -> 16B aligned
                const float* src = eWhh + r * 1000 + (c0 - 128);
                float4 a = *(const float4*)src;
                float4 bq = *(const float4*)(src + 4);
                v[0]=a.x; v[1]=a.y; v[2]=a.z; v[3]=a.w; v[4]=bq.x; v[5]=bq.y; v[6]=bq.z; v[7]=bq.w;
            } else if (c0 < 128) {
                const float* src = eWih + r * 101;
#pragma unroll
                for (int u = 0; u < 8; ++u) { int cc = c0 + u; if (cc < 101) v[u] = src[cc]; }
            }
        }
        bf16x8 o;
#pragma unroll
        for (int u = 0; u < 8; ++u) o[u] = (bf16_t)v[u];
        *(bf16x8*)(Wenc + (size_t)row * 1152 + c0) = o;
    } else if (b < 11520) {
        // A_enc: x into cols 0..100, zeros elsewhere (pad + h-slot).
        int gid = (b - 9216) * 256 + threadIdx.x;
        int row = gid / 144, grp = gid - row * 144;
        int c0  = grp * 8;
        float v[8];
#pragma unroll
        for (int u = 0; u < 8; ++u) v[u] = 0.0f;
        if (c0 < 101) {
            const float* src = x + (size_t)row * 101;
#pragma unroll
            for (int u = 0; u < 8; ++u) { int cc = c0 + u; if (cc < 101) v[u] = src[cc]; }
        }
        bf16x8 o;
#pragma unroll
        for (int u = 0; u < 8; ++u) o[u] = (bf16_t)v[u];
        *(bf16x8*)(Aenc + (size_t)row * 1152 + c0) = o;
    } else if (b < 12672) {
        // W_dec: 512 N-pos/layer, e in [0,128); orig row g*101+e (if e<101).
        // Cols: [dWih(0:1000) 0 dWhh(1024:1125) 0].
        int gid = (b - 11520) * 256 + threadIdx.x;
        int row = gid / 144, grp = gid - row * 144;
        int l = row >> 9, p = row & 511;
        int g = (p >> 4) & 3, e = ((p >> 6) << 4) + (p & 15);
        int c0 = grp * 8;
        float v[8];
#pragma unroll
        for (int u = 0; u < 8; ++u) v[u] = 0.0f;
        if (e < 101) {
            size_t r = (size_t)l * 404 + g * 101 + e;
            if (c0 < 1000) {  // c0 mult of 8 and <1000 -> c0<=992, full 8 in range
                const float* src = dWih + r * 1000 + c0;
                float4 a = *(const float4*)src;
                float4 bq = *(const float4*)(src + 4);
                v[0]=a.x; v[1]=a.y; v[2]=a.z; v[3]=a.w; v[4]=bq.x; v[5]=bq.y; v[6]=bq.z; v[7]=bq.w;
            } else if (c0 >= 1024 && c0 < 1128) {
                const float* src = dWhh + r * 101;
#pragma unroll
                for (int u = 0; u < 8; ++u) { int cc = c0 + u; if (cc < 1125) v[u] = src[cc - 1024]; }
            }
        }
        bf16x8 o;
#pragma unroll
        for (int u = 0; u < 8; ++u) o[u] = (bf16_t)v[u];
        *(bf16x8*)(Wdec + (size_t)row * 1152 + c0) = o;
    } else {
        // Biases: bse (16384) then bsd (2048).
        int idx = (b - 12672) * 256 + threadIdx.x;
        if (idx < 16384) {
            int l = idx >> 12, p = idx & 4095;
            int g = (p >> 4) & 3, e = ((p >> 6) << 4) + (p & 15);
            bse[idx] = (e < 1000) ? (ebih[l * 4000 + g * 1000 + e] + ebhh[l * 4000 + g * 1000 + e]) : 0.0f;
        } else {
            int k = idx - 16384;
            int l = k >> 9, p = k & 511;
            int g = (p >> 4) & 3, e = ((p >> 6) << 4) + (p & 15);
            bsd[k] = (e < 101) ? (dbih[l * 404 + g * 101 + e] + dbhh[l * 404 + g * 101 + e]) : 0.0f;
        }
    }
}

// ---------------- log_softmax over 101 valid cols (stride 128) ----------------
__global__ void log_softmax_k(const float* __restrict__ h, float* __restrict__ out)
{
    int row = blockIdx.x;
    int l   = threadIdx.x;          // 64
    const float* hr = h + (size_t)row * 128;
    float v1 = (l < 101)      ? hr[l]      : -INFINITY;
    float v2 = (l + 64 < 101) ? hr[l + 64] : -INFINITY;
    float m = fmaxf(v1, v2);
#pragma unroll
    for (int off = 32; off > 0; off >>= 1) m = fmaxf(m, __shfl_down(m, off));
    m = __shfl(m, 0);
    float ev = ((l < 101) ? __expf(v1 - m) : 0.0f) + ((l + 64 < 101) ? __expf(v2 - m) : 0.0f);
#pragma unroll
    for (int off = 32; off > 0; off >>= 1) ev += __shfl_down(ev, off);
    float lse = m + __logf(__shfl(ev, 0));
    float* orow = out + (size_t)row * 101;
    if (l < 101)      orow[l]      = v1 - lse;
    if (l + 64 < 101) orow[l + 64] = v2 - lse;
}

extern "C" void kernel_launch(void* const* d_in, const int* in_sizes, int n_in,
                              void* d_out, int out_size, void* d_ws, size_t ws_size,
                              hipStream_t stream)
{
    (void)in_sizes; (void)n_in; (void)out_size; (void)ws_size;
    const float* x    = (const float*)d_in[0];
    const float* eWih = (const float*)d_in[1];
    const float* eWhh = (const float*)d_in[2];
    const float* ebih = (const float*)d_in[3];
    const float* ebhh = (const float*)d_in[4];
    const float* dWih = (const float*)d_in[5];
    const float* dWhh = (const float*)d_in[6];
    const float* dbih = (const float*)d_in[7];
    const float* dbhh = (const float*)d_in[8];

    char* ws = (char*)d_ws;
    bf16_t* Aenc = (bf16_t*)(ws);                 // 4096*1152*2   =  9,437,184
    bf16_t* Wenc = (bf16_t*)(ws + 9437184);       // 4*4096*1152*2 = 37,748,736
    bf16_t* Adec = (bf16_t*)(ws + 47185920);      //                  9,437,184
    bf16_t* Wdec = (bf16_t*)(ws + 56623104);      // 4*512*1152*2  =  4,718,592
    float*  bse  = (float*) (ws + 61341696);      // 4*4096*4      =     65,536
    float*  bsd  = (float*) (ws + 61407232);      // 4*512*4       =      8,192
    float*  cenc = (float*) (ws + 61415424);      // 4096*1024*4   = 16,777,216
    float*  cdec = (float*) (ws + 78192640);      // 4096*128*4    =   2,097,152
    float*  hdec = (float*) (ws + 80289792);      // 4096*128*4    =   2,097,152  (end 82,386,944)

    // ws re-poisoned 0xAA every call: every buffer is written before read
    // (czero=1 layer-0 gemms fully write cenc/cdec; K-trim means the
    // un-initialized Adec h-slot / Aenc h-slot are never read at layer 0).
    pack_all<<<12744, 256, 0, stream>>>(x, eWih, eWhh, ebih, ebhh, dWih, dWhh, dbih, dbhh,
                                        Aenc, Wenc, Wdec, bse, bsd);

    // Encoder: 4 layers, fused gates-GEMM + LSTM cell (BM=128, 1024 blocks).
    // Layer 0: h == 0 so the h@Whh^T term (cols 128..1151) is all-zero ->
    // K=128 (x part only); c-in is zero -> czero=1 skips the load.
    for (int l = 0; l < 4; ++l) {
        gemm_lstm<128><<<dim3(32, 32), 256, 0, stream>>>(
            Aenc, Wenc + (size_t)l * 4096 * 1152, bse + l * 4096,
            cenc, 1024,
            (l < 3) ? Aenc : Adec, 1152, (l < 3) ? 128 : 0, nullptr,
            (l == 0) ? 128 : 1152, 1152, 1152, (l == 3) ? 1 : 0, (l == 0) ? 1 : 0);
    }
    // Decoder: 4 layers. BM=32 -> grid(4,128)=512 blocks = 2 blocks/CU so
    // the per-K-step stage drains of one block overlap the other's MFMAs.
    // Layer 0: h == 0 -> K=1024 (enc part only), czero=1.
    for (int l = 0; l < 4; ++l) {
        gemm_lstm<32><<<dim3(4, 128), 256, 0, stream>>>(
            Adec, Wdec + (size_t)l * 512 * 1152, bsd + l * 512,
            cdec, 128,
            (l < 3) ? Adec : nullptr, 1152, 1024, (l == 3) ? hdec : nullptr,
            (l == 0) ? 1024 : 1152, 1152, 1152, 0, (l == 0) ? 1 : 0);
    }
    log_softmax_k<<<4096, 64, 0, stream>>>(hdec, (float*)d_out);
}